// Round 1
// baseline (1375.053 us; speedup 1.0000x reference)
//
#include <hip/hip_runtime.h>
#include <math.h>

#define H_DIM 180
#define W_DIM 360
#define CH    256
#define NHEAD 8
#define HD    32   // head dim
#define MPIX  (H_DIM * W_DIM)   // 64800

// ---------------------------------------------------------------------------
// Kernel A: qkv = x @ w_qkv + b_qkv, scattered to [3][NH][M][32], q pre-scaled
// M=64800, K=256, N=768. Classic 64x64 LDS-tiled fp32 GEMM, 4x4 per thread.
// ---------------------------------------------------------------------------
__global__ __launch_bounds__(256)
void qkv_gemm_kernel(const float* __restrict__ X,   // [M][256]
                     const float* __restrict__ W,   // [256][768]
                     const float* __restrict__ B,   // [768]
                     float* __restrict__ qkv,       // [3][NH][M][32]
                     int M)
{
    const int K = 256, N = 768;
    __shared__ float As[16][68];  // [k][m], pad to 68 floats (16B-aligned rows)
    __shared__ float Bs[16][68];  // [k][n]

    const int tid = threadIdx.x;
    const int bm = blockIdx.y * 64;
    const int bn = blockIdx.x * 64;
    const int tx = tid & 15;      // 16 col-groups
    const int ty = tid >> 4;      // 16 row-groups

    float acc[4][4] = {};

    for (int k0 = 0; k0 < K; k0 += 16) {
        // load A-tile: 64 rows x 16 k (coalesced 64B per 16 lanes)
        {
            const int kk   = tid & 15;
            const int mrow = tid >> 4;   // 0..15
            #pragma unroll
            for (int r = 0; r < 4; ++r) {
                const int m = bm + mrow + r * 16;
                As[kk][mrow + r * 16] = (m < M) ? X[(size_t)m * K + k0 + kk] : 0.f;
            }
        }
        // load B-tile: 16 k x 64 n (coalesced 256B per wave)
        {
            const int nn = tid & 63;
            const int kk = tid >> 6;     // 0..3
            #pragma unroll
            for (int r = 0; r < 4; ++r) {
                Bs[kk + r * 4][nn] = W[(size_t)(k0 + kk + r * 4) * N + bn + nn];
            }
        }
        __syncthreads();
        #pragma unroll
        for (int kk = 0; kk < 16; ++kk) {
            float a[4], b[4];
            #pragma unroll
            for (int i = 0; i < 4; ++i) a[i] = As[kk][ty * 4 + i];
            #pragma unroll
            for (int j = 0; j < 4; ++j) b[j] = Bs[kk][tx * 4 + j];
            #pragma unroll
            for (int i = 0; i < 4; ++i)
                #pragma unroll
                for (int j = 0; j < 4; ++j)
                    acc[i][j] += a[i] * b[j];
        }
        __syncthreads();
    }

    // epilogue: add bias, scale q, scatter to [which][head][pixel][jd]
    const float scale = 0.17677669529663687f;  // 1/sqrt(32)
    #pragma unroll
    for (int i = 0; i < 4; ++i) {
        const int m = bm + ty * 4 + i;
        if (m >= M) continue;
        #pragma unroll
        for (int j = 0; j < 4; ++j) {
            const int c = bn + tx * 4 + j;
            float val = acc[i][j] + B[c];
            const int which = c >> 8;        // 0=q 1=k 2=v
            const int n     = (c >> 5) & 7;  // head
            const int jd    = c & 31;        // dim within head
            if (which == 0) val *= scale;
            qkv[(((size_t)which * NHEAD + n) * M + m) * HD + jd] = val;
        }
    }
}

// ---------------------------------------------------------------------------
// Kernel B: neighborhood attention. One thread per (pixel, head).
// block = 256 threads = 8 heads x 32 w-positions, one h row per block-y.
// q pre-scaled; k/v layout [NH][H][W][32]; circular wrap in W; clamped in H.
// ---------------------------------------------------------------------------
__global__ __launch_bounds__(256)
void natten_attn_kernel(const float* __restrict__ q,
                        const float* __restrict__ k,
                        const float* __restrict__ v,
                        const float* __restrict__ rpb,   // [8][13][13]
                        float* __restrict__ out)         // [H][W][256]
{
    const int tid = threadIdx.x;
    const int n   = tid >> 5;           // head 0..7
    const int wl  = tid & 31;           // local w
    const int w   = blockIdx.x * 32 + wl;
    const int h   = blockIdx.y;
    if (w >= W_DIM) return;

    int sh = h - 3;
    if (sh < 0) sh = 0;
    if (sh > H_DIM - 7) sh = H_DIM - 7;
    const int rh0 = sh - h + 6;         // rpb row base (3 except near edges)

    // load q vector (pre-scaled) into registers
    const float4* qp = reinterpret_cast<const float4*>(
        q + (((size_t)n * H_DIM + h) * W_DIM + w) * HD);
    float4 qr[8];
    #pragma unroll
    for (int t = 0; t < 8; ++t) qr[t] = qp[t];

    float sc[49];
    #pragma unroll
    for (int oi = 0; oi < 7; ++oi) {
        const int row = sh + oi;
        #pragma unroll
        for (int oj = 0; oj < 7; ++oj) {
            int col = w + oj - 3;
            if (col < 0) col += W_DIM;
            else if (col >= W_DIM) col -= W_DIM;
            const float4* kp = reinterpret_cast<const float4*>(
                k + (((size_t)n * H_DIM + row) * W_DIM + col) * HD);
            float dot = 0.f;
            #pragma unroll
            for (int t = 0; t < 8; ++t) {
                const float4 kv = kp[t];
                dot += qr[t].x * kv.x + qr[t].y * kv.y
                     + qr[t].z * kv.z + qr[t].w * kv.w;
            }
            sc[oi * 7 + oj] = dot + rpb[((size_t)n * 13 + rh0 + oi) * 13 + 3 + oj];
        }
    }

    // softmax over the 49 neighbors
    float mx = sc[0];
    #pragma unroll
    for (int i = 1; i < 49; ++i) mx = fmaxf(mx, sc[i]);
    float ssum = 0.f;
    #pragma unroll
    for (int i = 0; i < 49; ++i) { sc[i] = __expf(sc[i] - mx); ssum += sc[i]; }
    const float inv = 1.f / ssum;

    // weighted sum of v
    float4 acc[8];
    #pragma unroll
    for (int t = 0; t < 8; ++t) acc[t] = make_float4(0.f, 0.f, 0.f, 0.f);
    #pragma unroll
    for (int oi = 0; oi < 7; ++oi) {
        const int row = sh + oi;
        #pragma unroll
        for (int oj = 0; oj < 7; ++oj) {
            int col = w + oj - 3;
            if (col < 0) col += W_DIM;
            else if (col >= W_DIM) col -= W_DIM;
            const float a = sc[oi * 7 + oj] * inv;
            const float4* vp = reinterpret_cast<const float4*>(
                v + (((size_t)n * H_DIM + row) * W_DIM + col) * HD);
            #pragma unroll
            for (int t = 0; t < 8; ++t) {
                const float4 vv = vp[t];
                acc[t].x += a * vv.x; acc[t].y += a * vv.y;
                acc[t].z += a * vv.z; acc[t].w += a * vv.w;
            }
        }
    }

    // write merged-head output [H][W][256]
    float4* op = reinterpret_cast<float4*>(
        out + ((size_t)h * W_DIM + w) * CH + n * HD);
    #pragma unroll
    for (int t = 0; t < 8; ++t) op[t] = acc[t];
}

// ---------------------------------------------------------------------------
// Kernel C: out = attn @ w_proj + b_proj. M=64800, K=256, N=256.
// ---------------------------------------------------------------------------
__global__ __launch_bounds__(256)
void proj_gemm_kernel(const float* __restrict__ X,   // [M][256]
                      const float* __restrict__ W,   // [256][256]
                      const float* __restrict__ B,   // [256]
                      float* __restrict__ out,       // [M][256]
                      int M)
{
    const int K = 256, N = 256;
    __shared__ float As[16][68];
    __shared__ float Bs[16][68];

    const int tid = threadIdx.x;
    const int bm = blockIdx.y * 64;
    const int bn = blockIdx.x * 64;
    const int tx = tid & 15;
    const int ty = tid >> 4;

    float acc[4][4] = {};

    for (int k0 = 0; k0 < K; k0 += 16) {
        {
            const int kk   = tid & 15;
            const int mrow = tid >> 4;
            #pragma unroll
            for (int r = 0; r < 4; ++r) {
                const int m = bm + mrow + r * 16;
                As[kk][mrow + r * 16] = (m < M) ? X[(size_t)m * K + k0 + kk] : 0.f;
            }
        }
        {
            const int nn = tid & 63;
            const int kk = tid >> 6;
            #pragma unroll
            for (int r = 0; r < 4; ++r) {
                Bs[kk + r * 4][nn] = W[(size_t)(k0 + kk + r * 4) * N + bn + nn];
            }
        }
        __syncthreads();
        #pragma unroll
        for (int kk = 0; kk < 16; ++kk) {
            float a[4], b[4];
            #pragma unroll
            for (int i = 0; i < 4; ++i) a[i] = As[kk][ty * 4 + i];
            #pragma unroll
            for (int j = 0; j < 4; ++j) b[j] = Bs[kk][tx * 4 + j];
            #pragma unroll
            for (int i = 0; i < 4; ++i)
                #pragma unroll
                for (int j = 0; j < 4; ++j)
                    acc[i][j] += a[i] * b[j];
        }
        __syncthreads();
    }

    #pragma unroll
    for (int i = 0; i < 4; ++i) {
        const int m = bm + ty * 4 + i;
        if (m >= M) continue;
        #pragma unroll
        for (int j = 0; j < 4; ++j) {
            const int c = bn + tx * 4 + j;
            out[(size_t)m * N + c] = acc[i][j] + B[c];
        }
    }
}

// ---------------------------------------------------------------------------
extern "C" void kernel_launch(void* const* d_in, const int* in_sizes, int n_in,
                              void* d_out, int out_size, void* d_ws, size_t ws_size,
                              hipStream_t stream)
{
    const float* x      = (const float*)d_in[0];  // [1,180,360,256]
    const float* w_qkv  = (const float*)d_in[1];  // [256,768]
    const float* b_qkv  = (const float*)d_in[2];  // [768]
    const float* rpb    = (const float*)d_in[3];  // [8,13,13]
    const float* w_proj = (const float*)d_in[4];  // [256,256]
    const float* b_proj = (const float*)d_in[5];  // [256]
    float* out = (float*)d_out;                   // [180,360,256]

    const int M = MPIX;  // 64800
    float* qbuf = (float*)d_ws;                                  // [8][M][32]
    float* kbuf = qbuf + (size_t)NHEAD * M * HD;                 // [8][M][32]
    float* vbuf = kbuf + (size_t)NHEAD * M * HD;                 // [8][M][32]
    float* attn = vbuf + (size_t)NHEAD * M * HD;                 // [M][256]

    const size_t need = ((size_t)3 * NHEAD * M * HD + (size_t)M * CH) * sizeof(float);
    if (ws_size < need) return;  // insufficient scratch: fail loudly via validation

    dim3 blk(256);
    qkv_gemm_kernel<<<dim3(768 / 64, (M + 63) / 64), blk, 0, stream>>>(
        x, w_qkv, b_qkv, qbuf, M);
    natten_attn_kernel<<<dim3((W_DIM + 31) / 32, H_DIM), blk, 0, stream>>>(
        qbuf, kbuf, vbuf, rpb, attn);
    proj_gemm_kernel<<<dim3(256 / 64, (M + 63) / 64), blk, 0, stream>>>(
        attn, w_proj, b_proj, out, M);
}

// Round 2
// 764.136 us; speedup vs baseline: 1.7995x; 1.7995x over previous
//
#include <hip/hip_runtime.h>
#include <hip/hip_bf16.h>
#include <math.h>

#define H_DIM 180
#define W_DIM 360
#define CH    256
#define NHEAD 8
#define HD    32   // head dim
#define MPIX  (H_DIM * W_DIM)   // 64800

// ---------------------------------------------------------------------------
// Kernel A: qkv = x @ w_qkv + b_qkv. q -> fp32-scaled? NO: q,k,v all bf16 now.
// q is pre-scaled by 1/sqrt(32) then converted. Layout [NH][H*W][32] each.
// ---------------------------------------------------------------------------
__global__ __launch_bounds__(256)
void qkv_gemm_kernel(const float* __restrict__ X,   // [M][256]
                     const float* __restrict__ W,   // [256][768]
                     const float* __restrict__ B,   // [768]
                     __hip_bfloat16* __restrict__ qout,  // [8][M][32]
                     __hip_bfloat16* __restrict__ kout,  // [8][M][32]
                     __hip_bfloat16* __restrict__ vout,  // [8][M][32]
                     int M)
{
    const int K = 256, N = 768;
    __shared__ float As[16][68];
    __shared__ float Bs[16][68];

    const int tid = threadIdx.x;
    const int bm = blockIdx.y * 64;
    const int bn = blockIdx.x * 64;
    const int tx = tid & 15;
    const int ty = tid >> 4;

    float acc[4][4] = {};

    for (int k0 = 0; k0 < K; k0 += 16) {
        {
            const int kk   = tid & 15;
            const int mrow = tid >> 4;
            #pragma unroll
            for (int r = 0; r < 4; ++r) {
                const int m = bm + mrow + r * 16;
                As[kk][mrow + r * 16] = (m < M) ? X[(size_t)m * K + k0 + kk] : 0.f;
            }
        }
        {
            const int nn = tid & 63;
            const int kk = tid >> 6;
            #pragma unroll
            for (int r = 0; r < 4; ++r) {
                Bs[kk + r * 4][nn] = W[(size_t)(k0 + kk + r * 4) * N + bn + nn];
            }
        }
        __syncthreads();
        #pragma unroll
        for (int kk = 0; kk < 16; ++kk) {
            float a[4], b[4];
            #pragma unroll
            for (int i = 0; i < 4; ++i) a[i] = As[kk][ty * 4 + i];
            #pragma unroll
            for (int j = 0; j < 4; ++j) b[j] = Bs[kk][tx * 4 + j];
            #pragma unroll
            for (int i = 0; i < 4; ++i)
                #pragma unroll
                for (int j = 0; j < 4; ++j)
                    acc[i][j] += a[i] * b[j];
        }
        __syncthreads();
    }

    const float scale = 0.17677669529663687f;  // 1/sqrt(32)
    #pragma unroll
    for (int i = 0; i < 4; ++i) {
        const int m = bm + ty * 4 + i;
        if (m >= M) continue;
        #pragma unroll
        for (int j = 0; j < 4; ++j) {
            const int c = bn + tx * 4 + j;
            float val = acc[i][j] + B[c];
            const int which = c >> 8;        // 0=q 1=k 2=v
            const int n     = (c >> 5) & 7;  // head
            const int jd    = c & 31;        // dim within head
            const size_t idx = (((size_t)n * M + m)) * HD + jd;
            if (which == 0)      qout[idx] = __float2bfloat16(val * scale);
            else if (which == 1) kout[idx] = __float2bfloat16(val);
            else                 vout[idx] = __float2bfloat16(val);
        }
    }
}

// ---------------------------------------------------------------------------
// Kernel B: neighborhood attention, LDS-staged bf16 k/v.
// block = 256 threads = one head x (8h x 32w) pixel tile.
// Stages (14 rows x 38 cols x 32 d) bf16 k and v tiles (34 KB each) with an
// XOR bank swizzle, plus the head's 13x13 rpb slice.
// ---------------------------------------------------------------------------
#define KROWS 14
#define KCOLS 38
#define KUNITS (KROWS * KCOLS * 4)   // 2128 uint4 (16B) units per tensor

__device__ __forceinline__ float bflo(unsigned int u) {
    return __uint_as_float(u << 16);
}
__device__ __forceinline__ float bfhi(unsigned int u) {
    return __uint_as_float(u & 0xffff0000u);
}

__global__ __launch_bounds__(256, 2)
void natten_attn_kernel(const __hip_bfloat16* __restrict__ q,  // [8][180*360][32]
                        const uint4* __restrict__ kb,          // bf16 as uint4
                        const uint4* __restrict__ vb,
                        const float* __restrict__ rpb,         // [8][13][13]
                        float* __restrict__ out)               // [H][W][256]
{
    __shared__ uint4 ks[KUNITS];
    __shared__ uint4 vs[KUNITS];
    __shared__ float rpbs[169];

    const int tid = threadIdx.x;
    const int n  = blockIdx.z;
    const int w0 = blockIdx.x * 32;
    const int h0 = blockIdx.y * 8;

    int r0 = h0 - 3;
    if (r0 < 0) r0 = 0;
    if (r0 > H_DIM - 7) r0 = H_DIM - 7;

    if (tid < 169) rpbs[tid] = rpb[n * 169 + tid];

    // stage k/v halo tile: rows r0..r0+13 (clamped), cols w0-3..w0+34 (wrapped)
    for (int u = tid; u < KUNITS; u += 256) {
        const int row = u / (KCOLS * 4);
        const int rem = u - row * (KCOLS * 4);
        const int col = rem >> 2;
        const int t   = rem & 3;
        int grow = r0 + row;
        if (grow > H_DIM - 1) grow = H_DIM - 1;   // rows past 179 are never read
        int gcol = w0 - 3 + col;
        if (gcol < 0) gcol += W_DIM;
        else if (gcol >= W_DIM) gcol -= W_DIM;
        const size_t gidx = (((size_t)n * H_DIM + grow) * W_DIM + gcol) * 4 + t;
        const int lidx = (row * KCOLS + col) * 4 + (t ^ ((col >> 1) & 3));
        ks[lidx] = kb[gidx];
        vs[lidx] = vb[gidx];
    }
    __syncthreads();

    const int hl = tid >> 5;       // 0..7
    const int wl = tid & 31;       // 0..31
    const int h = h0 + hl;
    const int w = w0 + wl;
    if (h >= H_DIM || w >= W_DIM) return;   // after the only __syncthreads

    int sh = h - 3;
    if (sh < 0) sh = 0;
    if (sh > H_DIM - 7) sh = H_DIM - 7;
    const int ri0 = sh - r0;           // 0..7
    const int rh0 = sh - h + 6;        // rpb row base

    // load q (bf16, pre-scaled) -> 32 floats in registers
    const uint4* qp = reinterpret_cast<const uint4*>(
        q + (((size_t)n * MPIX + (size_t)h * W_DIM + w)) * HD);
    float qr[32];
    #pragma unroll
    for (int t = 0; t < 4; ++t) {
        const uint4 qq = qp[t];
        qr[t*8+0] = bflo(qq.x); qr[t*8+1] = bfhi(qq.x);
        qr[t*8+2] = bflo(qq.y); qr[t*8+3] = bfhi(qq.y);
        qr[t*8+4] = bflo(qq.z); qr[t*8+5] = bfhi(qq.z);
        qr[t*8+6] = bflo(qq.w); qr[t*8+7] = bfhi(qq.w);
    }

    float sc[49];
    #pragma unroll
    for (int oi = 0; oi < 7; ++oi) {
        const int rb = (ri0 + oi) * (KCOLS * 4);
        #pragma unroll
        for (int oj = 0; oj < 7; ++oj) {
            const int cl = wl + oj;            // 0..37
            const int base = rb + cl * 4;
            const int sw = (cl >> 1) & 3;
            float dot = 0.f;
            #pragma unroll
            for (int t = 0; t < 4; ++t) {
                const uint4 kk = ks[base + (t ^ sw)];
                dot += bflo(kk.x) * qr[t*8+0] + bfhi(kk.x) * qr[t*8+1];
                dot += bflo(kk.y) * qr[t*8+2] + bfhi(kk.y) * qr[t*8+3];
                dot += bflo(kk.z) * qr[t*8+4] + bfhi(kk.z) * qr[t*8+5];
                dot += bflo(kk.w) * qr[t*8+6] + bfhi(kk.w) * qr[t*8+7];
            }
            sc[oi * 7 + oj] = dot + rpbs[(rh0 + oi) * 13 + 3 + oj];
        }
    }

    // softmax over 49 neighbors
    float mx = sc[0];
    #pragma unroll
    for (int i = 1; i < 49; ++i) mx = fmaxf(mx, sc[i]);
    float ssum = 0.f;
    #pragma unroll
    for (int i = 0; i < 49; ++i) { sc[i] = __expf(sc[i] - mx); ssum += sc[i]; }
    const float inv = 1.f / ssum;

    // weighted sum of v
    float acc[32];
    #pragma unroll
    for (int t = 0; t < 32; ++t) acc[t] = 0.f;
    #pragma unroll
    for (int oi = 0; oi < 7; ++oi) {
        const int rb = (ri0 + oi) * (KCOLS * 4);
        #pragma unroll
        for (int oj = 0; oj < 7; ++oj) {
            const int cl = wl + oj;
            const int base = rb + cl * 4;
            const int sw = (cl >> 1) & 3;
            const float a = sc[oi * 7 + oj] * inv;
            #pragma unroll
            for (int t = 0; t < 4; ++t) {
                const uint4 vv = vs[base + (t ^ sw)];
                acc[t*8+0] += a * bflo(vv.x); acc[t*8+1] += a * bfhi(vv.x);
                acc[t*8+2] += a * bflo(vv.y); acc[t*8+3] += a * bfhi(vv.y);
                acc[t*8+4] += a * bflo(vv.z); acc[t*8+5] += a * bfhi(vv.z);
                acc[t*8+6] += a * bflo(vv.w); acc[t*8+7] += a * bfhi(vv.w);
            }
        }
    }

    // write merged-head output [H][W][256]
    float4* op = reinterpret_cast<float4*>(
        out + ((size_t)h * W_DIM + w) * CH + n * HD);
    #pragma unroll
    for (int t = 0; t < 8; ++t)
        op[t] = make_float4(acc[t*4+0], acc[t*4+1], acc[t*4+2], acc[t*4+3]);
}

// ---------------------------------------------------------------------------
// Kernel C: out = attn @ w_proj + b_proj. M=64800, K=256, N=256. fp32.
// ---------------------------------------------------------------------------
__global__ __launch_bounds__(256)
void proj_gemm_kernel(const float* __restrict__ X,   // [M][256]
                      const float* __restrict__ W,   // [256][256]
                      const float* __restrict__ B,   // [256]
                      float* __restrict__ out,       // [M][256]
                      int M)
{
    const int K = 256, N = 256;
    __shared__ float As[16][68];
    __shared__ float Bs[16][68];

    const int tid = threadIdx.x;
    const int bm = blockIdx.y * 64;
    const int bn = blockIdx.x * 64;
    const int tx = tid & 15;
    const int ty = tid >> 4;

    float acc[4][4] = {};

    for (int k0 = 0; k0 < K; k0 += 16) {
        {
            const int kk   = tid & 15;
            const int mrow = tid >> 4;
            #pragma unroll
            for (int r = 0; r < 4; ++r) {
                const int m = bm + mrow + r * 16;
                As[kk][mrow + r * 16] = (m < M) ? X[(size_t)m * K + k0 + kk] : 0.f;
            }
        }
        {
            const int nn = tid & 63;
            const int kk = tid >> 6;
            #pragma unroll
            for (int r = 0; r < 4; ++r) {
                Bs[kk + r * 4][nn] = W[(size_t)(k0 + kk + r * 4) * N + bn + nn];
            }
        }
        __syncthreads();
        #pragma unroll
        for (int kk = 0; kk < 16; ++kk) {
            float a[4], b[4];
            #pragma unroll
            for (int i = 0; i < 4; ++i) a[i] = As[kk][ty * 4 + i];
            #pragma unroll
            for (int j = 0; j < 4; ++j) b[j] = Bs[kk][tx * 4 + j];
            #pragma unroll
            for (int i = 0; i < 4; ++i)
                #pragma unroll
                for (int j = 0; j < 4; ++j)
                    acc[i][j] += a[i] * b[j];
        }
        __syncthreads();
    }

    #pragma unroll
    for (int i = 0; i < 4; ++i) {
        const int m = bm + ty * 4 + i;
        if (m >= M) continue;
        #pragma unroll
        for (int j = 0; j < 4; ++j) {
            const int c = bn + tx * 4 + j;
            out[(size_t)m * N + c] = acc[i][j] + B[c];
        }
    }
}

// ---------------------------------------------------------------------------
extern "C" void kernel_launch(void* const* d_in, const int* in_sizes, int n_in,
                              void* d_out, int out_size, void* d_ws, size_t ws_size,
                              hipStream_t stream)
{
    const float* x      = (const float*)d_in[0];  // [1,180,360,256]
    const float* w_qkv  = (const float*)d_in[1];  // [256,768]
    const float* b_qkv  = (const float*)d_in[2];  // [768]
    const float* rpb    = (const float*)d_in[3];  // [8,13,13]
    const float* w_proj = (const float*)d_in[4];  // [256,256]
    const float* b_proj = (const float*)d_in[5];  // [256]
    float* out = (float*)d_out;                   // [180,360,256]

    const int M = MPIX;  // 64800
    const size_t nelem = (size_t)NHEAD * M * HD;  // 16,588,800

    __hip_bfloat16* qbuf = (__hip_bfloat16*)d_ws;            // [8][M][32] bf16
    __hip_bfloat16* kbuf = qbuf + nelem;
    __hip_bfloat16* vbuf = kbuf + nelem;
    float* attn = (float*)(vbuf + nelem);                    // [M][256] f32

    const size_t need = 3 * nelem * sizeof(__hip_bfloat16)
                      + (size_t)M * CH * sizeof(float);
    if (ws_size < need) return;

    dim3 blk(256);
    qkv_gemm_kernel<<<dim3(768 / 64, (M + 63) / 64), blk, 0, stream>>>(
        x, w_qkv, b_qkv, qbuf, kbuf, vbuf, M);
    natten_attn_kernel<<<dim3(W_DIM / 32 + (W_DIM % 32 ? 1 : 0),
                              (H_DIM + 7) / 8, NHEAD), blk, 0, stream>>>(
        qbuf, (const uint4*)kbuf, (const uint4*)vbuf, rpb, attn);
    proj_gemm_kernel<<<dim3(256 / 64, (M + 63) / 64), blk, 0, stream>>>(
        attn, w_proj, b_proj, out, M);
}

// Round 3
// 565.099 us; speedup vs baseline: 2.4333x; 1.3522x over previous
//
#include <hip/hip_runtime.h>
#include <hip/hip_fp16.h>
#include <math.h>

#define H_DIM 180
#define W_DIM 360
#define CH    256
#define NHEAD 8
#define HD    32
#define MPIX  (H_DIM * W_DIM)   // 64800
#define KDIM  256

typedef _Float16 f16x8 __attribute__((ext_vector_type(8)));
typedef float    f32x4 __attribute__((ext_vector_type(4)));

// ---------------------------------------------------------------------------
// Kernel 0: fp32 -> fp16 conversions. job y=0: X (8 elems/thread);
// y=1: w_qkv -> Wqt[768][256] (transposed); y=2: w_proj -> Wpt[256][256].
// ---------------------------------------------------------------------------
__global__ __launch_bounds__(256)
void convert_kernel(const float* __restrict__ X, const float* __restrict__ Wq,
                    const float* __restrict__ Wp, _Float16* __restrict__ Xh,
                    _Float16* __restrict__ Wqt, _Float16* __restrict__ Wpt)
{
    const int tid = blockIdx.x * 256 + threadIdx.x;
    if (blockIdx.y == 0) {
        const float4* X4 = reinterpret_cast<const float4*>(X);
        const float4 a = X4[tid * 2];
        const float4 b = X4[tid * 2 + 1];
        __half2 h0 = __floats2half2_rn(a.x, a.y);
        __half2 h1 = __floats2half2_rn(a.z, a.w);
        __half2 h2 = __floats2half2_rn(b.x, b.y);
        __half2 h3 = __floats2half2_rn(b.z, b.w);
        uint4 o;
        o.x = *reinterpret_cast<unsigned*>(&h0);
        o.y = *reinterpret_cast<unsigned*>(&h1);
        o.z = *reinterpret_cast<unsigned*>(&h2);
        o.w = *reinterpret_cast<unsigned*>(&h3);
        reinterpret_cast<uint4*>(Xh)[tid] = o;
    } else if (blockIdx.y == 1) {
        if (tid < 768 * 256) {
            const int n = tid >> 8, k = tid & 255;
            Wqt[tid] = (_Float16)Wq[k * 768 + n];
        }
    } else {
        if (tid < 256 * 256) {
            const int n = tid >> 8, k = tid & 255;
            Wpt[tid] = (_Float16)Wp[k * 256 + n];
        }
    }
}

// ---------------------------------------------------------------------------
// MFMA fp16 GEMM, 128x128 tile, 4 waves (64x64 each), BK=64, K=256.
// A [M][256] f16 row-major, Bt [NB][256] f16 (pre-transposed weights).
// MODE 0: qkv epilogue (bias, q-scale, scatter to [8][M][32] f16 q/k/v).
// MODE 1: proj epilogue (bias, fp32 out [M][NB]).
// ---------------------------------------------------------------------------
template<int NB, int MODE>
__global__ __launch_bounds__(256)
void mfma_gemm_kernel(const _Float16* __restrict__ A,
                      const _Float16* __restrict__ Bt,
                      const float* __restrict__ bias,
                      _Float16* __restrict__ qo, _Float16* __restrict__ ko,
                      _Float16* __restrict__ vo, float* __restrict__ outf,
                      int M)
{
    __shared__ __align__(16) _Float16 Alds[128 * 64];
    __shared__ __align__(16) _Float16 Blds[128 * 64];

    const int tid  = threadIdx.x;
    const int wid  = tid >> 6;
    const int lane = tid & 63;
    const int bn   = blockIdx.x * 128;
    const int bm   = blockIdx.y * 128;
    const int wr   = wid >> 1;      // wave row 0..1
    const int wc   = wid & 1;       // wave col 0..1

    f32x4 acc[4][4] = {};

    const int srow  = lane >> 3;        // 0..7 row within 8-row chunk
    const int sunit = (lane & 7) * 16;  // byte offset within 128B row

    for (int k0 = 0; k0 < KDIM; k0 += 64) {
        #pragma unroll
        for (int i = 0; i < 4; ++i) {
            const int chunk = i * 4 + wid;       // 0..15, wave-uniform
            const int row   = chunk * 8 + srow;  // 0..127
            int am = bm + row;
            am = (am < M) ? am : (M - 1);
            const char* asrc = (const char*)(A + (size_t)am * KDIM + k0) + sunit;
            __builtin_amdgcn_global_load_lds(
                (const __attribute__((address_space(1))) void*)asrc,
                (__attribute__((address_space(3))) void*)((char*)Alds + chunk * 1024),
                16, 0, 0);
            const char* bsrc = (const char*)(Bt + (size_t)(bn + row) * KDIM + k0) + sunit;
            __builtin_amdgcn_global_load_lds(
                (const __attribute__((address_space(1))) void*)bsrc,
                (__attribute__((address_space(3))) void*)((char*)Blds + chunk * 1024),
                16, 0, 0);
        }
        __syncthreads();
        #pragma unroll
        for (int kk = 0; kk < 64; kk += 32) {
            const int ko2 = kk + (lane >> 4) * 8;
            f16x8 af[4], bf[4];
            #pragma unroll
            for (int t = 0; t < 4; ++t) {
                af[t] = *(const f16x8*)&Alds[(wr * 64 + t * 16 + (lane & 15)) * 64 + ko2];
                bf[t] = *(const f16x8*)&Blds[(wc * 64 + t * 16 + (lane & 15)) * 64 + ko2];
            }
            #pragma unroll
            for (int fi = 0; fi < 4; ++fi)
                #pragma unroll
                for (int fj = 0; fj < 4; ++fj)
                    acc[fi][fj] = __builtin_amdgcn_mfma_f32_16x16x32_f16(
                        af[fi], bf[fj], acc[fi][fj], 0, 0, 0);
        }
        __syncthreads();
    }

    // epilogue — C/D layout: col = lane&15, row = (lane>>4)*4 + j
    const int lc  = lane & 15;
    const int lrb = (lane >> 4) * 4;
    if (MODE == 0) {
        const float scale = 0.17677669529663687f;  // 1/sqrt(32)
        #pragma unroll
        for (int fj = 0; fj < 4; ++fj) {
            const int c = bn + wc * 64 + fj * 16 + lc;
            const float bv = bias[c];
            const int which = c >> 8;
            const int head  = (c >> 5) & 7;
            const int jd    = c & 31;
            _Float16* dst = (which == 0) ? qo : (which == 1) ? ko : vo;
            const float scl = (which == 0) ? scale : 1.0f;
            #pragma unroll
            for (int fi = 0; fi < 4; ++fi) {
                #pragma unroll
                for (int j = 0; j < 4; ++j) {
                    const int m = bm + wr * 64 + fi * 16 + lrb + j;
                    if (m < M)
                        dst[((size_t)head * M + m) * HD + jd] =
                            (_Float16)((acc[fi][fj][j] + bv) * scl);
                }
            }
        }
    } else {
        #pragma unroll
        for (int fj = 0; fj < 4; ++fj) {
            const int c = bn + wc * 64 + fj * 16 + lc;
            const float bv = bias[c];
            #pragma unroll
            for (int fi = 0; fi < 4; ++fi) {
                #pragma unroll
                for (int j = 0; j < 4; ++j) {
                    const int m = bm + wr * 64 + fi * 16 + lrb + j;
                    if (m < M)
                        outf[(size_t)m * NB + c] = acc[fi][fj][j] + bv;
                }
            }
        }
    }
}

// ---------------------------------------------------------------------------
// Attention: one block = (head, 8h x 32w pixel tile). Single LDS buffer
// time-shared: stage K -> scores+softmax -> stage V -> PV. fp16 k/v/q.
// ---------------------------------------------------------------------------
#define KROWS 14
#define KCOLS 38
#define KUNITS (KROWS * KCOLS * 4)   // 2128 x 16B

__device__ __forceinline__ float2 cvt2(unsigned u) {
    __half2 h = *reinterpret_cast<__half2*>(&u);
    return __half22float2(h);
}

__global__ __launch_bounds__(256, 3)
void natten_attn_kernel(const _Float16* __restrict__ q,   // [8][M][32] f16
                        const uint4* __restrict__ kb,     // f16 as uint4
                        const uint4* __restrict__ vb,
                        const float* __restrict__ rpb,    // [8][13][13]
                        _Float16* __restrict__ outh)      // [M][256] f16
{
    __shared__ uint4 kvs[KUNITS];
    __shared__ float rpbs[169];

    const int tid = threadIdx.x;
    const int n  = blockIdx.z;
    const int w0 = blockIdx.x * 32;
    const int h0 = blockIdx.y * 8;

    int r0 = h0 - 3;
    if (r0 < 0) r0 = 0;
    if (r0 > H_DIM - 7) r0 = H_DIM - 7;

    if (tid < 169) rpbs[tid] = rpb[n * 169 + tid];

    // ---- phase 1: stage K tile ----
    for (int u = tid; u < KUNITS; u += 256) {
        const int row = u / (KCOLS * 4);
        const int rem = u - row * (KCOLS * 4);
        const int col = rem >> 2;
        const int t   = rem & 3;
        int grow = r0 + row;
        if (grow > H_DIM - 1) grow = H_DIM - 1;
        int gcol = w0 - 3 + col;
        if (gcol < 0) gcol += W_DIM;
        else if (gcol >= W_DIM) gcol -= W_DIM;
        kvs[(row * KCOLS + col) * 4 + (t ^ ((col >> 1) & 3))] =
            kb[(((size_t)n * H_DIM + grow) * W_DIM + gcol) * 4 + t];
    }
    __syncthreads();

    const int hl = tid >> 5;
    const int wl = tid & 31;
    const int h = h0 + hl;
    const int w = w0 + wl;
    const bool valid = (h < H_DIM) && (w < W_DIM);

    float sc[49];
    float inv = 0.f;
    int ri0 = 0;

    if (valid) {
        int sh = h - 3;
        if (sh < 0) sh = 0;
        if (sh > H_DIM - 7) sh = H_DIM - 7;
        ri0 = sh - r0;
        const int rh0 = sh - h + 6;

        // q (pre-scaled fp16) -> 32 floats
        const uint4* qp = reinterpret_cast<const uint4*>(
            q + ((size_t)n * MPIX + (size_t)h * W_DIM + w) * HD);
        float qr[32];
        #pragma unroll
        for (int t = 0; t < 4; ++t) {
            const uint4 qq = qp[t];
            float2 f;
            f = cvt2(qq.x); qr[t*8+0] = f.x; qr[t*8+1] = f.y;
            f = cvt2(qq.y); qr[t*8+2] = f.x; qr[t*8+3] = f.y;
            f = cvt2(qq.z); qr[t*8+4] = f.x; qr[t*8+5] = f.y;
            f = cvt2(qq.w); qr[t*8+6] = f.x; qr[t*8+7] = f.y;
        }

        #pragma unroll
        for (int oi = 0; oi < 7; ++oi) {
            const int rb = (ri0 + oi) * (KCOLS * 4);
            #pragma unroll
            for (int oj = 0; oj < 7; ++oj) {
                const int cl = wl + oj;
                const int base = rb + cl * 4;
                const int sw = (cl >> 1) & 3;
                float dot = 0.f;
                #pragma unroll
                for (int t = 0; t < 4; ++t) {
                    const uint4 kk = kvs[base + (t ^ sw)];
                    float2 f;
                    f = cvt2(kk.x); dot += f.x * qr[t*8+0] + f.y * qr[t*8+1];
                    f = cvt2(kk.y); dot += f.x * qr[t*8+2] + f.y * qr[t*8+3];
                    f = cvt2(kk.z); dot += f.x * qr[t*8+4] + f.y * qr[t*8+5];
                    f = cvt2(kk.w); dot += f.x * qr[t*8+6] + f.y * qr[t*8+7];
                }
                sc[oi * 7 + oj] = dot + rpbs[(rh0 + oi) * 13 + 3 + oj];
            }
        }

        float mx = sc[0];
        #pragma unroll
        for (int i = 1; i < 49; ++i) mx = fmaxf(mx, sc[i]);
        float ssum = 0.f;
        #pragma unroll
        for (int i = 0; i < 49; ++i) { sc[i] = __expf(sc[i] - mx); ssum += sc[i]; }
        inv = 1.f / ssum;
    }
    __syncthreads();

    // ---- phase 2: stage V tile into the same buffer ----
    for (int u = tid; u < KUNITS; u += 256) {
        const int row = u / (KCOLS * 4);
        const int rem = u - row * (KCOLS * 4);
        const int col = rem >> 2;
        const int t   = rem & 3;
        int grow = r0 + row;
        if (grow > H_DIM - 1) grow = H_DIM - 1;
        int gcol = w0 - 3 + col;
        if (gcol < 0) gcol += W_DIM;
        else if (gcol >= W_DIM) gcol -= W_DIM;
        kvs[(row * KCOLS + col) * 4 + (t ^ ((col >> 1) & 3))] =
            vb[(((size_t)n * H_DIM + grow) * W_DIM + gcol) * 4 + t];
    }
    __syncthreads();

    if (!valid) return;

    float acc[32];
    #pragma unroll
    for (int t = 0; t < 32; ++t) acc[t] = 0.f;
    #pragma unroll
    for (int oi = 0; oi < 7; ++oi) {
        const int rb = (ri0 + oi) * (KCOLS * 4);
        #pragma unroll
        for (int oj = 0; oj < 7; ++oj) {
            const int cl = wl + oj;
            const int base = rb + cl * 4;
            const int sw = (cl >> 1) & 3;
            const float a = sc[oi * 7 + oj] * inv;
            #pragma unroll
            for (int t = 0; t < 4; ++t) {
                const uint4 vv = kvs[base + (t ^ sw)];
                float2 f;
                f = cvt2(vv.x); acc[t*8+0] += a * f.x; acc[t*8+1] += a * f.y;
                f = cvt2(vv.y); acc[t*8+2] += a * f.x; acc[t*8+3] += a * f.y;
                f = cvt2(vv.z); acc[t*8+4] += a * f.x; acc[t*8+5] += a * f.y;
                f = cvt2(vv.w); acc[t*8+6] += a * f.x; acc[t*8+7] += a * f.y;
            }
        }
    }

    // write fp16 attention output [M][256] (proj GEMM input)
    uint4 o[4];
    #pragma unroll
    for (int t = 0; t < 4; ++t) {
        __half2 p0 = __floats2half2_rn(acc[t*8+0], acc[t*8+1]);
        __half2 p1 = __floats2half2_rn(acc[t*8+2], acc[t*8+3]);
        __half2 p2 = __floats2half2_rn(acc[t*8+4], acc[t*8+5]);
        __half2 p3 = __floats2half2_rn(acc[t*8+6], acc[t*8+7]);
        o[t].x = *reinterpret_cast<unsigned*>(&p0);
        o[t].y = *reinterpret_cast<unsigned*>(&p1);
        o[t].z = *reinterpret_cast<unsigned*>(&p2);
        o[t].w = *reinterpret_cast<unsigned*>(&p3);
    }
    uint4* op = reinterpret_cast<uint4*>(
        outh + (((size_t)h * W_DIM + w) * CH + n * HD));
    #pragma unroll
    for (int t = 0; t < 4; ++t) op[t] = o[t];
}

// ---------------------------------------------------------------------------
extern "C" void kernel_launch(void* const* d_in, const int* in_sizes, int n_in,
                              void* d_out, int out_size, void* d_ws, size_t ws_size,
                              hipStream_t stream)
{
    const float* x      = (const float*)d_in[0];
    const float* w_qkv  = (const float*)d_in[1];
    const float* b_qkv  = (const float*)d_in[2];
    const float* rpb    = (const float*)d_in[3];
    const float* w_proj = (const float*)d_in[4];
    const float* b_proj = (const float*)d_in[5];
    float* out = (float*)d_out;

    const int M = MPIX;                       // 64800
    const size_t nelem = (size_t)M * KDIM;    // 16,588,800

    _Float16* Xh  = (_Float16*)d_ws;          // [M][256]
    _Float16* Wqt = Xh  + nelem;              // [768][256]
    _Float16* Wpt = Wqt + 768 * 256;          // [256][256]
    _Float16* qb  = Wpt + 256 * 256;          // [8][M][32]
    _Float16* kb  = qb  + nelem;
    _Float16* vb  = kb  + nelem;
    _Float16* ah  = vb  + nelem;              // [M][256] attn out f16

    const size_t need = (5 * nelem + 768 * 256 + 256 * 256) * sizeof(_Float16);
    if (ws_size < need) return;

    dim3 blk(256);
    convert_kernel<<<dim3(8100, 3), blk, 0, stream>>>(x, w_qkv, w_proj, Xh, Wqt, Wpt);

    mfma_gemm_kernel<768, 0><<<dim3(6, 507), blk, 0, stream>>>(
        Xh, Wqt, b_qkv, qb, kb, vb, nullptr, M);

    natten_attn_kernel<<<dim3(12, 23, NHEAD), blk, 0, stream>>>(
        qb, (const uint4*)kb, (const uint4*)vb, rpb, ah);

    mfma_gemm_kernel<256, 1><<<dim3(2, 507), blk, 0, stream>>>(
        ah, Wpt, b_proj, nullptr, nullptr, nullptr, out, M);
}

// Round 4
// 243.050 us; speedup vs baseline: 5.6575x; 2.3250x over previous
//
#include <hip/hip_runtime.h>
#include <hip/hip_fp16.h>
#include <math.h>

#define H_DIM 180
#define W_DIM 360
#define CH    256
#define NHEAD 8
#define HD    32
#define MPIX  (H_DIM * W_DIM)   // 64800
#define KDIM  256

typedef _Float16 f16x8 __attribute__((ext_vector_type(8)));
typedef _Float16 h2    __attribute__((ext_vector_type(2)));
typedef float    f32x4 __attribute__((ext_vector_type(4)));

#if __has_builtin(__builtin_amdgcn_fdot2)
#define HAS_FDOT2 1
#else
#define HAS_FDOT2 0
#endif

// ---------------------------------------------------------------------------
// Kernel 0: fp32 -> fp16 conversions. y=0: X; y=1: w_qkv -> Wqt[768][256]
// (transposed); y=2: w_proj -> Wpt[256][256] (transposed).
// ---------------------------------------------------------------------------
__global__ __launch_bounds__(256)
void convert_kernel(const float* __restrict__ X, const float* __restrict__ Wq,
                    const float* __restrict__ Wp, _Float16* __restrict__ Xh,
                    _Float16* __restrict__ Wqt, _Float16* __restrict__ Wpt)
{
    const int tid = blockIdx.x * 256 + threadIdx.x;
    if (blockIdx.y == 0) {
        const float4* X4 = reinterpret_cast<const float4*>(X);
        const float4 a = X4[tid * 2];
        const float4 b = X4[tid * 2 + 1];
        __half2 h0 = __floats2half2_rn(a.x, a.y);
        __half2 h1 = __floats2half2_rn(a.z, a.w);
        __half2 h2_ = __floats2half2_rn(b.x, b.y);
        __half2 h3 = __floats2half2_rn(b.z, b.w);
        uint4 o;
        o.x = *reinterpret_cast<unsigned*>(&h0);
        o.y = *reinterpret_cast<unsigned*>(&h1);
        o.z = *reinterpret_cast<unsigned*>(&h2_);
        o.w = *reinterpret_cast<unsigned*>(&h3);
        reinterpret_cast<uint4*>(Xh)[tid] = o;
    } else if (blockIdx.y == 1) {
        if (tid < 768 * 256) {
            const int n = tid >> 8, k = tid & 255;
            Wqt[tid] = (_Float16)Wq[k * 768 + n];
        }
    } else {
        if (tid < 256 * 256) {
            const int n = tid >> 8, k = tid & 255;
            Wpt[tid] = (_Float16)Wp[k * 256 + n];
        }
    }
}

// ---------------------------------------------------------------------------
// MFMA fp16 GEMM, 128x128 tile, 4 waves (64x64 each), BK=64, K=256.
// MODE 0: qkv epilogue (bias, q-scale, scatter to [8][M][32] f16 q/k/v).
// MODE 1: proj epilogue (bias, fp32 out [M][NB]).
// ---------------------------------------------------------------------------
template<int NB, int MODE>
__global__ __launch_bounds__(256)
void mfma_gemm_kernel(const _Float16* __restrict__ A,
                      const _Float16* __restrict__ Bt,
                      const float* __restrict__ bias,
                      _Float16* __restrict__ qo, _Float16* __restrict__ ko,
                      _Float16* __restrict__ vo, float* __restrict__ outf,
                      int M)
{
    __shared__ __align__(16) _Float16 Alds[128 * 64];
    __shared__ __align__(16) _Float16 Blds[128 * 64];

    const int tid  = threadIdx.x;
    const int wid  = tid >> 6;
    const int lane = tid & 63;
    const int bn   = blockIdx.x * 128;
    const int bm   = blockIdx.y * 128;
    const int wr   = wid >> 1;
    const int wc   = wid & 1;

    f32x4 acc[4][4] = {};

    const int srow  = lane >> 3;
    const int sunit = (lane & 7) * 16;

    for (int k0 = 0; k0 < KDIM; k0 += 64) {
        #pragma unroll
        for (int i = 0; i < 4; ++i) {
            const int chunk = i * 4 + wid;
            const int row   = chunk * 8 + srow;
            int am = bm + row;
            am = (am < M) ? am : (M - 1);
            const char* asrc = (const char*)(A + (size_t)am * KDIM + k0) + sunit;
            __builtin_amdgcn_global_load_lds(
                (const __attribute__((address_space(1))) void*)asrc,
                (__attribute__((address_space(3))) void*)((char*)Alds + chunk * 1024),
                16, 0, 0);
            const char* bsrc = (const char*)(Bt + (size_t)(bn + row) * KDIM + k0) + sunit;
            __builtin_amdgcn_global_load_lds(
                (const __attribute__((address_space(1))) void*)bsrc,
                (__attribute__((address_space(3))) void*)((char*)Blds + chunk * 1024),
                16, 0, 0);
        }
        __syncthreads();
        #pragma unroll
        for (int kk = 0; kk < 64; kk += 32) {
            const int ko2 = kk + (lane >> 4) * 8;
            f16x8 af[4], bf[4];
            #pragma unroll
            for (int t = 0; t < 4; ++t) {
                af[t] = *(const f16x8*)&Alds[(wr * 64 + t * 16 + (lane & 15)) * 64 + ko2];
                bf[t] = *(const f16x8*)&Blds[(wc * 64 + t * 16 + (lane & 15)) * 64 + ko2];
            }
            #pragma unroll
            for (int fi = 0; fi < 4; ++fi)
                #pragma unroll
                for (int fj = 0; fj < 4; ++fj)
                    acc[fi][fj] = __builtin_amdgcn_mfma_f32_16x16x32_f16(
                        af[fi], bf[fj], acc[fi][fj], 0, 0, 0);
        }
        __syncthreads();
    }

    const int lc  = lane & 15;
    const int lrb = (lane >> 4) * 4;
    if (MODE == 0) {
        const float scale = 0.17677669529663687f;
        #pragma unroll
        for (int fj = 0; fj < 4; ++fj) {
            const int c = bn + wc * 64 + fj * 16 + lc;
            const float bv = bias[c];
            const int which = c >> 8;
            const int head  = (c >> 5) & 7;
            const int jd    = c & 31;
            _Float16* dst = (which == 0) ? qo : (which == 1) ? ko : vo;
            const float scl = (which == 0) ? scale : 1.0f;
            #pragma unroll
            for (int fi = 0; fi < 4; ++fi) {
                #pragma unroll
                for (int j = 0; j < 4; ++j) {
                    const int m = bm + wr * 64 + fi * 16 + lrb + j;
                    if (m < M)
                        dst[((size_t)head * M + m) * HD + jd] =
                            (_Float16)((acc[fi][fj][j] + bv) * scl);
                }
            }
        }
    } else {
        #pragma unroll
        for (int fj = 0; fj < 4; ++fj) {
            const int c = bn + wc * 64 + fj * 16 + lc;
            const float bv = bias[c];
            #pragma unroll
            for (int fi = 0; fi < 4; ++fi) {
                #pragma unroll
                for (int j = 0; j < 4; ++j) {
                    const int m = bm + wr * 64 + fi * 16 + lrb + j;
                    if (m < M)
                        outf[(size_t)m * NB + c] = acc[fi][fj][j] + bv;
                }
            }
        }
    }
}

// ---------------------------------------------------------------------------
// Attention. One block = (head, 8h x 32w tile). Single 34 KB LDS buffer
// time-shared K then V. QK via v_dot2_f32_f16; PV via fma_mix pattern.
// ---------------------------------------------------------------------------
#define KROWS 14
#define KCOLS 38
#define KUNITS (KROWS * KCOLS * 4)   // 2128 x 16B

__device__ __forceinline__ void stage_tile(const uint4* __restrict__ src,
                                           uint4* __restrict__ dst,
                                           int n, int r0, int w0, int tid)
{
    for (int u = tid; u < KUNITS; u += 256) {
        const int row = u / (KCOLS * 4);
        const int rem = u - row * (KCOLS * 4);
        const int col = rem >> 2;
        const int t   = rem & 3;
        int grow = r0 + row;
        if (grow > H_DIM - 1) grow = H_DIM - 1;   // never read, safe addr
        int gcol = w0 - 3 + col;
        if (gcol < 0) gcol += W_DIM;
        else if (gcol >= W_DIM) gcol -= W_DIM;
        dst[(row * KCOLS + col) * 4 + (t ^ ((col >> 1) & 3))] =
            src[(((size_t)n * H_DIM + grow) * W_DIM + gcol) * 4 + t];
    }
}

__device__ __forceinline__ float qkdot8(uint4 kk, const h2* qh, float acc)
{
    h2 k0 = __builtin_bit_cast(h2, kk.x);
    h2 k1 = __builtin_bit_cast(h2, kk.y);
    h2 k2 = __builtin_bit_cast(h2, kk.z);
    h2 k3 = __builtin_bit_cast(h2, kk.w);
#if HAS_FDOT2
    acc = __builtin_amdgcn_fdot2(k0, qh[0], acc, false);
    acc = __builtin_amdgcn_fdot2(k1, qh[1], acc, false);
    acc = __builtin_amdgcn_fdot2(k2, qh[2], acc, false);
    acc = __builtin_amdgcn_fdot2(k3, qh[3], acc, false);
#else
    acc += (float)k0.x * (float)qh[0].x + (float)k0.y * (float)qh[0].y;
    acc += (float)k1.x * (float)qh[1].x + (float)k1.y * (float)qh[1].y;
    acc += (float)k2.x * (float)qh[2].x + (float)k2.y * (float)qh[2].y;
    acc += (float)k3.x * (float)qh[3].x + (float)k3.y * (float)qh[3].y;
#endif
    return acc;
}

__global__ __launch_bounds__(256)
void natten_attn_kernel(const _Float16* __restrict__ q,   // [8][M][32]
                        const uint4* __restrict__ kb,
                        const uint4* __restrict__ vb,
                        const float* __restrict__ rpb,    // [8][13][13]
                        _Float16* __restrict__ outh)      // [M][256]
{
    __shared__ uint4 kvs[KUNITS];
    __shared__ float rpbs[169];

    const int tid = threadIdx.x;
    const int n  = blockIdx.z;
    const int w0 = blockIdx.x * 32;
    const int h0 = blockIdx.y * 8;

    int r0 = h0 - 3;
    if (r0 < 0) r0 = 0;
    if (r0 > H_DIM - 7) r0 = H_DIM - 7;

    if (tid < 169) rpbs[tid] = rpb[n * 169 + tid];

    // ---- phase 1: stage K ----
    stage_tile(kb, kvs, n, r0, w0, tid);
    __syncthreads();

    const int hl = tid >> 5;
    const int wl = tid & 31;
    const int h = h0 + hl;
    const int w = w0 + wl;
    const bool valid = (h < H_DIM) && (w < W_DIM);

    float sc[49];
    float inv = 0.f;
    int ri0 = 0;

    if (valid) {
        int sh = h - 3;
        if (sh < 0) sh = 0;
        if (sh > H_DIM - 7) sh = H_DIM - 7;
        ri0 = sh - r0;
        const int rh0 = sh - h + 6;

        // q (pre-scaled f16) kept packed: 16 half2 = 16 VGPRs
        const uint4* qp = reinterpret_cast<const uint4*>(
            q + ((size_t)n * MPIX + (size_t)h * W_DIM + w) * HD);
        h2 qh[16];
        #pragma unroll
        for (int t = 0; t < 4; ++t) {
            const uint4 qq = qp[t];
            qh[t*4+0] = __builtin_bit_cast(h2, qq.x);
            qh[t*4+1] = __builtin_bit_cast(h2, qq.y);
            qh[t*4+2] = __builtin_bit_cast(h2, qq.z);
            qh[t*4+3] = __builtin_bit_cast(h2, qq.w);
        }

        #pragma unroll
        for (int oi = 0; oi < 7; ++oi) {
            const int rb = (ri0 + oi) * (KCOLS * 4);
            #pragma unroll
            for (int oj = 0; oj < 7; ++oj) {
                const int cl = wl + oj;
                const int base = rb + cl * 4;
                const int sw = (cl >> 1) & 3;
                float dot = rpbs[(rh0 + oi) * 13 + 3 + oj];
                #pragma unroll
                for (int t = 0; t < 4; ++t)
                    dot = qkdot8(kvs[base + (t ^ sw)], qh + t * 4, dot);
                sc[oi * 7 + oj] = dot;
            }
        }

        float mx = sc[0];
        #pragma unroll
        for (int i = 1; i < 49; ++i) mx = fmaxf(mx, sc[i]);
        float ssum = 0.f;
        #pragma unroll
        for (int i = 0; i < 49; ++i) { sc[i] = __expf(sc[i] - mx); ssum += sc[i]; }
        inv = 1.f / ssum;
    }
    __syncthreads();

    // ---- phase 2: stage V into the same buffer ----
    stage_tile(vb, kvs, n, r0, w0, tid);
    __syncthreads();

    if (!valid) return;

    // PV: accumulate raw exp weights; normalize at the end.
    float acc[32];
    #pragma unroll
    for (int t = 0; t < 32; ++t) acc[t] = 0.f;
    #pragma unroll
    for (int oi = 0; oi < 7; ++oi) {
        const int rb = (ri0 + oi) * (KCOLS * 4);
        #pragma unroll
        for (int oj = 0; oj < 7; ++oj) {
            const int cl = wl + oj;
            const int base = rb + cl * 4;
            const int sw = (cl >> 1) & 3;
            const float a = sc[oi * 7 + oj];
            #pragma unroll
            for (int t = 0; t < 4; ++t) {
                const uint4 vv = kvs[base + (t ^ sw)];
                h2 v0 = __builtin_bit_cast(h2, vv.x);
                h2 v1 = __builtin_bit_cast(h2, vv.y);
                h2 v2 = __builtin_bit_cast(h2, vv.z);
                h2 v3 = __builtin_bit_cast(h2, vv.w);
                acc[t*8+0] += a * (float)v0.x; acc[t*8+1] += a * (float)v0.y;
                acc[t*8+2] += a * (float)v1.x; acc[t*8+3] += a * (float)v1.y;
                acc[t*8+4] += a * (float)v2.x; acc[t*8+5] += a * (float)v2.y;
                acc[t*8+6] += a * (float)v3.x; acc[t*8+7] += a * (float)v3.y;
            }
        }
    }

    uint4 o[4];
    #pragma unroll
    for (int t = 0; t < 4; ++t) {
        h2 p0 = { (_Float16)(acc[t*8+0] * inv), (_Float16)(acc[t*8+1] * inv) };
        h2 p1 = { (_Float16)(acc[t*8+2] * inv), (_Float16)(acc[t*8+3] * inv) };
        h2 p2 = { (_Float16)(acc[t*8+4] * inv), (_Float16)(acc[t*8+5] * inv) };
        h2 p3 = { (_Float16)(acc[t*8+6] * inv), (_Float16)(acc[t*8+7] * inv) };
        o[t].x = __builtin_bit_cast(unsigned, p0);
        o[t].y = __builtin_bit_cast(unsigned, p1);
        o[t].z = __builtin_bit_cast(unsigned, p2);
        o[t].w = __builtin_bit_cast(unsigned, p3);
    }
    uint4* op = reinterpret_cast<uint4*>(
        outh + (((size_t)h * W_DIM + w) * CH + n * HD));
    #pragma unroll
    for (int t = 0; t < 4; ++t) op[t] = o[t];
}

// ---------------------------------------------------------------------------
extern "C" void kernel_launch(void* const* d_in, const int* in_sizes, int n_in,
                              void* d_out, int out_size, void* d_ws, size_t ws_size,
                              hipStream_t stream)
{
    const float* x      = (const float*)d_in[0];
    const float* w_qkv  = (const float*)d_in[1];
    const float* b_qkv  = (const float*)d_in[2];
    const float* rpb    = (const float*)d_in[3];
    const float* w_proj = (const float*)d_in[4];
    const float* b_proj = (const float*)d_in[5];
    float* out = (float*)d_out;

    const int M = MPIX;
    const size_t nelem = (size_t)M * KDIM;

    _Float16* Xh  = (_Float16*)d_ws;
    _Float16* Wqt = Xh  + nelem;
    _Float16* Wpt = Wqt + 768 * 256;
    _Float16* qb  = Wpt + 256 * 256;
    _Float16* kb  = qb  + nelem;
    _Float16* vb  = kb  + nelem;
    _Float16* ah  = vb  + nelem;

    const size_t need = (5 * nelem + 768 * 256 + 256 * 256) * sizeof(_Float16);
    if (ws_size < need) return;

    dim3 blk(256);
    convert_kernel<<<dim3(8100, 3), blk, 0, stream>>>(x, w_qkv, w_proj, Xh, Wqt, Wpt);

    mfma_gemm_kernel<768, 0><<<dim3(6, 507), blk, 0, stream>>>(
        Xh, Wqt, b_qkv, qb, kb, vb, nullptr, M);

    natten_attn_kernel<<<dim3(12, 23, NHEAD), blk, 0, stream>>>(
        qb, (const uint4*)kb, (const uint4*)vb, rpb, ah);

    mfma_gemm_kernel<256, 1><<<dim3(2, 507), blk, 0, stream>>>(
        ah, Wpt, b_proj, nullptr, nullptr, nullptr, out, M);
}